// Round 1
// 888.454 us; speedup vs baseline: 1.1479x; 1.1479x over previous
//
#include <hip/hip_runtime.h>
#include <math.h>

#define SS   0.1f
#define THRC 0.01f   // LMBD * MU

typedef __attribute__((ext_vector_type(8))) short s16x8;
typedef __attribute__((ext_vector_type(4))) float f32x4;

__device__ __forceinline__ float b2f(unsigned short u){
  union{unsigned int i; float f;} v; v.i = ((unsigned int)u)<<16; return v.f;
}
__device__ __forceinline__ unsigned short f2b(float f){
  union{float f; unsigned int i;} v; v.f = f;
  return (unsigned short)((v.i + 0x7fffu + ((v.i>>16)&1u))>>16);  // RNE
}
__device__ __forceinline__ s16x8 as_s16x8(uint4 u){
  union{uint4 a; s16x8 b;} c; c.a = u; return c.b;
}
// 8 quads (16B each) per 128-row tile row; XOR swizzle -> <=2-way conflicts
__device__ __forceinline__ int swz8(int row, int q){ return (row<<3) | (q ^ (row&7)); }

enum { EPI_FIRST=0, EPI_UPDATE=1, EPI_PARTIAL=2, EPI_RES_NHWC=3, EPI_RES_FLAT=4 };

struct EpiM {
  unsigned short* C;            // dest (c / r / partial)
  const unsigned short* Y;      // y for UPDATE
  const unsigned short* Cprev;  // c_{t-1} for fused y-update
  unsigned short* Yout;         // fused y_{t+1} output (optional)
  const unsigned short* img;    // image for residual epilogues
  float coef;
  int lH, lW, lC;               // log2 geometry for NHWC residual
  int S_MN, Kc;                 // split-K
};

// ---------------- A-tile loaders: return 8 contiguous bf16 (16B) ----------------
struct LA_ident {
  const unsigned short* A; int K;
  __device__ void setz(int){}
  __device__ __forceinline__ uint4 ld(int m, int k8) const {
    return *(const uint4*)(A + (size_t)m*K + ((size_t)k8<<3));
  }
};
struct LA_nhwc {   // im2col, NHWC bf16, stride2 pad1 k4; k = (kh*4+kw)*C + i
  const unsigned short* img; int lH, lW, lC;
  __device__ void setz(int){}
  __device__ __forceinline__ uint4 ld(int m, int k8) const {
    int lWo = lW-1, lHo = lH-1;
    int wo = m & ((1<<lWo)-1); int t = m>>lWo; int ho = t & ((1<<lHo)-1); int b = t>>lHo;
    int k = k8<<3; int kk = k>>lC; int i = k & ((1<<lC)-1);
    int kw = kk&3, kh = kk>>2;
    int h = 2*ho + kh - 1, w = 2*wo + kw - 1;
    if ((unsigned)h >= (1u<<lH) || (unsigned)w >= (1u<<lW)) return make_uint4(0,0,0,0);
    return *(const uint4*)(img + (((((((size_t)b<<lH)|h)<<lW)|w))<<lC) + i);
  }
};
struct LA_yg {     // parity-class tconv gather of code y; k = (th*2+tw)*O + o
  const unsigned short* y; int lHo, lWo, lO, ph, pw;
  __device__ void setz(int z){ ph = z>>1; pw = z&1; }
  __device__ __forceinline__ uint4 ld(int m, int k8) const {
    int l = m & ((1<<lWo)-1); int t = m>>lWo; int j = t & ((1<<lHo)-1); int b = t>>lHo;
    int k = k8<<3; int tt = k>>lO; int o = k & ((1<<lO)-1);
    int th = tt>>1, tw = tt&1;
    int ho = ph ? (j+1-th) : (j-th);
    int wo = pw ? (l+1-tw) : (l-tw);
    if ((unsigned)ho >= (1u<<lHo) || (unsigned)wo >= (1u<<lWo)) return make_uint4(0,0,0,0);
    return *(const uint4*)(y + (((((((size_t)b<<lHo)|ho)<<lWo)|wo))<<lO) + o);
  }
};
struct LA_pad {    // layer-1 im2col from padded f32 NHWC4 [B][34][34][4]; k = (kh*4+kw)*4 + c
  const float* img;
  __device__ void setz(int){}
  __device__ __forceinline__ uint4 ld(int m, int k8) const {
    int wo = m&15, t = m>>4, ho = t&15, b = t>>4;
    int kh = k8>>1, kw0 = (k8&1)<<1;
    int h = 2*ho + kh, w = 2*wo + kw0;          // (-1 pad offset cancels +1)
    const float* p = img + (((size_t)b*34 + h)*34 + w)*4;
    float4 A0 = *(const float4*)p;
    float4 A1 = *(const float4*)(p+4);
    union{unsigned short s[8]; uint4 u;} r;
    r.s[0]=f2b(A0.x); r.s[1]=f2b(A0.y); r.s[2]=f2b(A0.z); r.s[3]=f2b(A0.w);
    r.s[4]=f2b(A1.x); r.s[5]=f2b(A1.y); r.s[6]=f2b(A1.z); r.s[7]=f2b(A1.w);
    return r.u;
  }
};

// -------- MFMA GEMM: 128x128 tile, BK=64, 8 waves (2x4), wave=64x32, 16x16x32 bf16 --------
// Software-pipelined: reg-prefetch next K-step, LDS double-buffer, ONE raw s_barrier
// per K-step with explicit lgkmcnt(0) fence; prefetched global loads stay in flight
// across the barrier (no vmcnt drain -> latency hidden under ds_read+MFMA).
template<class AL, int EPI>
__global__ __launch_bounds__(512)
void mgemm_k(AL al, const unsigned short* __restrict__ Bw, int M, int N, int K, EpiM ep)
{
  __shared__ uint4 As[2048];  // 2 x (128 rows x 8 quads), swizzled
  __shared__ uint4 Bs[2048];
  const int tid = threadIdx.x;
  const int bm = blockIdx.y<<7, bn = blockIdx.x<<7;
  const int z = blockIdx.z;
  int kb = 0, ke = K;
  const unsigned short* Bp = Bw;
  if (EPI == EPI_PARTIAL){ kb = z*ep.Kc; ke = kb + ep.Kc; }
  if (EPI == EPI_RES_NHWC){ Bp = Bw + (size_t)z*(size_t)N*K; al.setz(z); }

  f32x4 acc[4][2];
  #pragma unroll
  for (int i=0;i<4;++i)
    #pragma unroll
    for (int j=0;j<2;++j){ acc[i][j][0]=0.f; acc[i][j][1]=0.f; acc[i][j][2]=0.f; acc[i][j][3]=0.f; }

  const int lane = tid & 63, wid = tid >> 6;
  const int wm = (wid>>2)<<6, wn = (wid&3)<<5;     // wave tile 64x32
  const int fr = lane & 15, fq = lane >> 4;
  const int sr = tid>>3, sq = tid&7;               // staging: row, quad
  const int gn0 = bn+sr, gn1 = bn+sr+64;

  uint4 ra0, ra1, rb0, rb1;
  auto fetch = [&](int k0){
    int k8 = k0>>3;
    ra0 = al.ld(bm+sr,    k8+sq);
    ra1 = al.ld(bm+sr+64, k8+sq);
    uint4 b0 = make_uint4(0,0,0,0), b1 = make_uint4(0,0,0,0);
    if (gn0 < N) b0 = *(const uint4*)(Bp + (size_t)gn0*K + k0 + (sq<<3));
    if (gn1 < N) b1 = *(const uint4*)(Bp + (size_t)gn1*K + k0 + (sq<<3));
    rb0 = b0; rb1 = b1;
  };

  fetch(kb);                 // prologue: tile 0 in flight
  int buf = 0;
  for (int k0 = kb; k0 < ke; k0 += 64){
    const int base = buf<<10;
    // drain previous-iter loads (data dependency -> compiler-inserted vmcnt) and stage
    As[base | swz8(sr,   sq)] = ra0;
    As[base | swz8(sr+64,sq)] = ra1;
    Bs[base | swz8(sr,   sq)] = rb0;
    Bs[base | swz8(sr+64,sq)] = rb1;
    if (k0 + 64 < ke) fetch(k0 + 64);   // issue next tile; NOT waited here
    // producer fence: my ds_writes (and any stale ds_reads) retired before barrier
    asm volatile("s_waitcnt lgkmcnt(0)" ::: "memory");
    __builtin_amdgcn_s_barrier();
    __builtin_amdgcn_sched_barrier(0);  // keep ds_reads after the barrier (rule #18)
    #pragma unroll
    for (int half=0; half<2; ++half){
      const int qb = (half<<2) | fq;
      s16x8 af[4], bf[2];
      #pragma unroll
      for (int mi=0;mi<4;++mi) af[mi] = as_s16x8(As[base | swz8(wm + mi*16 + fr, qb)]);
      #pragma unroll
      for (int ni=0;ni<2;++ni) bf[ni] = as_s16x8(Bs[base | swz8(wn + ni*16 + fr, qb)]);
      #pragma unroll
      for (int mi=0;mi<4;++mi)
        #pragma unroll
        for (int ni=0;ni<2;++ni)
          acc[mi][ni] = __builtin_amdgcn_mfma_f32_16x16x32_bf16(af[mi], bf[ni], acc[mi][ni], 0,0,0);
    }
    buf ^= 1;
    // no trailing barrier: next iter writes the OTHER buffer; write-after-read on this
    // buffer (t+2 vs t) is fenced by iter t+1's lgkmcnt(0)+s_barrier.
  }

  // epilogue: D lane map col=lane&15, row=(lane>>4)*4+reg
  #pragma unroll
  for (int mi=0;mi<4;++mi){
    #pragma unroll
    for (int ni=0;ni<2;++ni){
      int n = bn + wn + ni*16 + fr;
      if (n >= N) continue;
      int mb = bm + wm + mi*16 + (fq<<2);
      #pragma unroll
      for (int r=0;r<4;++r){
        int m = mb + r;
        float a = acc[mi][ni][r];
        if (EPI == EPI_FIRST){
          float v = SS*a - THRC; v = v>0.f ? v : 0.f;
          ep.C[(size_t)m*N + n] = f2b(v);
        } else if (EPI == EPI_UPDATE){
          size_t idx = (size_t)m*N + n;
          float v = b2f(ep.Y[idx]) + SS*a - THRC; v = v>0.f ? v : 0.f;
          ep.C[idx] = f2b(v);
          if (ep.Yout) ep.Yout[idx] = f2b(v + ep.coef*(v - b2f(ep.Cprev[idx])));
        } else if (EPI == EPI_PARTIAL){
          ep.C[(size_t)z*ep.S_MN + (size_t)m*N + n] = f2b(a);
        } else if (EPI == EPI_RES_NHWC){
          int lWo = ep.lW-1, lHo = ep.lH-1;
          int l = m & ((1<<lWo)-1); int t = m>>lWo; int j = t & ((1<<lHo)-1); int b = t>>lHo;
          int h = 2*j + (z>>1), w = 2*l + (z&1);
          size_t ridx = (((((((size_t)b<<ep.lH)|h)<<ep.lW)|w))<<ep.lC) | n;
          ep.C[ridx] = f2b(b2f(ep.img[ridx]) - a);
        } else { // EPI_RES_FLAT
          size_t ridx = (size_t)m*N + n;
          ep.C[ridx] = f2b(b2f(ep.img[ridx]) - a);
        }
      }
    }
  }
}

// ---------------- weight normalization ----------------
// layer 1: w (128,3,4,4) -> wf1[o][k=(kh*4+kw)*4+c] (K=64, c=3 zero) ; wcolT[e=t*4+c][o] (N=64)
__global__ __launch_bounds__(64)
void wnorm1_k(const float* __restrict__ w, unsigned short* __restrict__ wf1,
              unsigned short* __restrict__ wcolT)
{
  int o = blockIdx.x, tid = threadIdx.x;
  __shared__ float red[64];
  float v = (tid < 48) ? w[(size_t)o*48 + tid] : 0.f;  // tid = c*16 + t
  red[tid] = v*v; __syncthreads();
  for (int d=32; d>0; d>>=1){ if (tid<d) red[tid] += red[tid+d]; __syncthreads(); }
  float nv = v * rsqrtf(red[0]);
  if (tid < 48){
    int c = tid>>4, t = tid&15;
    wf1[(size_t)o*64 + t*4 + c] = f2b(nv);
    wcolT[(size_t)(t*4+c)*128 + o] = f2b(nv);
  } else {
    int t = tid - 48;
    wf1[(size_t)o*64 + t*4 + 3] = 0;
    wcolT[(size_t)(t*4+3)*128 + o] = 0;
  }
}
// generic: w (O,Cin,4,4); wT[o][t*Cin+i] (fwd B), wclsT[cls][i][tt*O+o] (tconv B), wEO[e][o]
__global__ __launch_bounds__(256)
void wnormX_k(const float* __restrict__ w, int Cin, int O,
              unsigned short* __restrict__ wT, unsigned short* __restrict__ wclsT,
              unsigned short* __restrict__ wEO)
{
  int o = blockIdx.x, tid = threadIdx.x; int E = Cin*16;
  __shared__ float red[256];
  float s = 0.f;
  for (int e = tid; e < E; e += 256){ float v = w[(size_t)o*E + e]; s += v*v; }
  red[tid] = s; __syncthreads();
  for (int d=128; d>0; d>>=1){ if (tid<d) red[tid] += red[tid+d]; __syncthreads(); }
  float scale = rsqrtf(red[0]);
  for (int e = tid; e < E; e += 256){
    float v = w[(size_t)o*E + e] * scale;
    int i = e>>4, t = e&15, kh = t>>2, kw = t&3;
    int ee = t*Cin + i;
    if (wT)  wT[(size_t)o*E + ee] = f2b(v);
    if (wEO) wEO[(size_t)ee*O + o] = f2b(v);
    if (wclsT){
      int ph = (kh&1)^1, pw = (kw&1)^1, cls = ph*2+pw;
      int tt = (kh>>1)*2 + (kw>>1);
      wclsT[(((size_t)cls*Cin + i)*4 + tt)*O + o] = f2b(v);
    }
  }
}

// ---------------- small kernels ----------------
__global__ void splitk_shrink_k(const unsigned short* __restrict__ part,
                                const unsigned short* __restrict__ Y,
                                unsigned short* __restrict__ C,
                                unsigned short* __restrict__ Yout,
                                const unsigned short* __restrict__ Cprev,
                                float coef, int MN, int S)
{
  for (int i = blockIdx.x*blockDim.x + threadIdx.x; i < MN; i += gridDim.x*blockDim.x){
    float s = 0.f;
    for (int zz = 0; zz < S; ++zz) s += b2f(part[(size_t)zz*MN + i]);
    float v = (Y ? b2f(Y[i]) : 0.f) + SS*s - THRC; v = v>0.f ? v : 0.f;
    C[i] = f2b(v);
    if (Yout) Yout[i] = f2b(v + coef*(v - b2f(Cprev[i])));
  }
}

__global__ void pad_x_k(const float* __restrict__ x, float* __restrict__ xp){
  int idx = blockIdx.x*256 + threadIdx.x;
  if (idx >= 262144) return;
  int w = idx&31, t = idx>>5, h = t&31, b = t>>5;
  size_t src = (size_t)b*3072 + h*32 + w;
  float* d = xp + (((size_t)b*34 + h+1)*34 + w+1)*4;
  d[0] = x[src]; d[1] = x[src+1024]; d[2] = x[src+2048];
}

__global__ void l1_resid_k(const unsigned short* __restrict__ Col,
                           const float* __restrict__ x, float* __restrict__ r1p)
{
  int idx = blockIdx.x*256 + threadIdx.x;
  if (idx >= 262144) return;
  int w = idx&31, t = idx>>5, h = t&31, b = t>>5;
  float a0=0.f, a1=0.f, a2=0.f;
  #pragma unroll
  for (int kh=0; kh<4; ++kh){
    int hh = h+1-kh; if (hh & 1) continue; int ho = hh>>1; if ((unsigned)ho >= 16u) continue;
    #pragma unroll
    for (int kw=0; kw<4; ++kw){
      int ww = w+1-kw; if (ww & 1) continue; int wo = ww>>1; if ((unsigned)wo >= 16u) continue;
      int m = (b*16+ho)*16+wo;
      const unsigned short* cp = Col + (size_t)m*64 + (kh*4+kw)*4;
      a0 += b2f(cp[0]); a1 += b2f(cp[1]); a2 += b2f(cp[2]);
    }
  }
  size_t src = (size_t)b*3072 + h*32 + w;
  float* d = r1p + (((size_t)b*34 + h+1)*34 + w+1)*4;
  d[0] = x[src] - a0; d[1] = x[src+1024] - a1; d[2] = x[src+2048] - a2;
}

__global__ void bn_stats_k(const unsigned short* __restrict__ d, float* __restrict__ sums,
                           int rows, int O){
  for (int c = threadIdx.x; c < O; c += blockDim.x){
    float a = 0.f, b = 0.f;
    for (int r = blockIdx.x; r < rows; r += gridDim.x){
      float v = b2f(d[(size_t)r*O + c]); a += v; b += v*v;
    }
    atomicAdd(&sums[c], a); atomicAdd(&sums[O+c], b);
  }
}
__global__ void bn_apply_k(const unsigned short* __restrict__ d, const float* __restrict__ sums,
                           const float* __restrict__ g, const float* __restrict__ bta,
                           unsigned short* __restrict__ outp, int rows, int O, float inv_cnt){
  int total = rows*O;
  for (int i = blockIdx.x*blockDim.x + threadIdx.x; i < total; i += gridDim.x*blockDim.x){
    int c = i % O;
    float mean = sums[c]*inv_cnt;
    float var  = sums[O+c]*inv_cnt - mean*mean;
    float v = g[c]*(b2f(d[i])-mean)*rsqrtf(var + 1e-5f) + bta[c];
    outp[i] = f2b(v >= 0.f ? v : 0.2f*v);
  }
}

__global__ __launch_bounds__(256)
void norm_rows_k(const unsigned short* __restrict__ h, float* __restrict__ out){
  int row = blockIdx.x, tid = threadIdx.x;
  __shared__ float red[256];
  float v = b2f(h[(size_t)row*256 + tid]);
  red[tid] = v*v; __syncthreads();
  for (int d=128; d>0; d>>=1){ if (tid<d) red[tid] += red[tid+d]; __syncthreads(); }
  float nrm = sqrtf(red[0]); nrm = nrm > 1e-12f ? nrm : 1e-12f;
  out[(size_t)row*256 + tid] = v / nrm;
}

// ---------------- host ----------------
extern "C" void kernel_launch(void* const* d_in, const int* in_sizes, int n_in,
                              void* d_out, int out_size, void* d_ws, size_t ws_size,
                              hipStream_t stream)
{
  const float* x  = (const float*)d_in[0];
  const float* w1 = (const float*)d_in[1];
  const float* w2 = (const float*)d_in[2];
  const float* w3 = (const float*)d_in[3];
  const float* w4 = (const float*)d_in[4];
  const float* g2 = (const float*)d_in[5];
  const float* b2 = (const float*)d_in[6];
  const float* g3 = (const float*)d_in[7];
  const float* b3 = (const float*)d_in[8];
  float* out = (float*)d_out;

  char* p = (char*)d_ws;
  auto ah = [&](size_t n){ unsigned short* r = (unsigned short*)p; p += n*2; return r; };
  auto af = [&](size_t n){ float* r = (float*)p; p += n*4; return r; };

  unsigned short* wf1    = ah(128*64);
  unsigned short* wcol1T = ah(64*128);
  unsigned short* wT2    = ah((size_t)256*2048);
  unsigned short* wcls2  = ah((size_t)4*128*1024);
  unsigned short* wT3    = ah((size_t)512*4096);
  unsigned short* wcls3  = ah((size_t)4*256*2048);
  unsigned short* wT4    = ah((size_t)256*8192);
  unsigned short* wE4    = ah((size_t)8192*256);
  unsigned short* h1     = ah((size_t)8388608);
  unsigned short* h2     = ah((size_t)4194304);
  unsigned short* h3     = ah((size_t)2097152);
  unsigned short* cA     = ah((size_t)8388608);
  unsigned short* cB     = ah((size_t)8388608);
  unsigned short* yA     = ah((size_t)8388608);
  unsigned short* yB     = ah((size_t)8388608);
  unsigned short* rH     = ah((size_t)8388608);
  // union scratch region: L1 {Col 8.39MB + xp 4.74MB + r1p 4.74MB} / L3 {partL3 16.8MB} / L4 {partL4 4.2MB}
  char* regionA = p; p += 17858560;
  unsigned short* Col    = (unsigned short*)regionA;                       // 65536 x 64 bf16
  float*          xp     = (float*)(regionA + 8388608);                    // 256*34*34*4 f32
  float*          r1p    = (float*)(regionA + 8388608 + 4734976);
  unsigned short* partL3 = (unsigned short*)regionA;                       // 4 x 4096*512 bf16
  unsigned short* partL4 = (unsigned short*)regionA;                       // 32 x 65536 bf16
  float* bnsum = af(1024);

  double tk = 1.0; float coef[4] = {0.f,0.f,0.f,0.f};
  for (int t = 1; t < 4; ++t){
    double tkp = tk; tk = (1.0 + sqrt(1.0 + 4.0*tkp*tkp))*0.5;
    coef[t] = (float)((tkp - 1.0)/tk);
  }

  hipMemsetAsync(xp,  0, 4734976, stream);
  hipMemsetAsync(r1p, 0, 4734976, stream);
  pad_x_k<<<1024,256,0,stream>>>(x, xp);
  wnorm1_k<<<128, 64, 0, stream>>>(w1, wf1, wcol1T);
  wnormX_k<<<256,256,0,stream>>>(w2, 128, 256, wT2, wcls2, nullptr);
  wnormX_k<<<512,256,0,stream>>>(w3, 256, 512, wT3, wcls3, nullptr);
  wnormX_k<<<256,256,0,stream>>>(w4, 512, 256, wT4, nullptr, wE4);

  // ---------- Layer 1: padded f32 NHWC4 -> code (65536,128), K=64 ----------
  auto l1_fwd = [&](const float* src, const unsigned short* Y, const unsigned short* Cp,
                    unsigned short* Cout, unsigned short* Yout, float cf){
    LA_pad al{src};
    EpiM ep{}; ep.C=Cout; ep.Y=Y; ep.Cprev=Cp; ep.Yout=Yout; ep.coef=cf;
    dim3 g(1, 512, 1);
    if (Y) mgemm_k<LA_pad,EPI_UPDATE><<<g,512,0,stream>>>(al, wf1, 65536,128,64, ep);
    else   mgemm_k<LA_pad,EPI_FIRST ><<<g,512,0,stream>>>(al, wf1, 65536,128,64, ep);
  };
  auto l1_tconv = [&](const unsigned short* y){
    LA_ident al{y, 128};
    EpiM ep{}; ep.C=Col; ep.S_MN=0; ep.Kc=128;
    mgemm_k<LA_ident,EPI_PARTIAL><<<dim3(1,512,1),512,0,stream>>>(al, wcol1T, 65536,64,128, ep);
    l1_resid_k<<<1024,256,0,stream>>>(Col, x, r1p);
  };
  l1_fwd(xp,  nullptr, nullptr, cA, nullptr, 0.f);     // c0 (=y1)
  l1_tconv(cA);
  l1_fwd(r1p, cA, cA, cB, yA, coef[2]);                // c1, y2
  l1_tconv(yA);
  l1_fwd(r1p, yA, cB, cA, yB, coef[3]);                // c2, y3
  l1_tconv(yB);
  l1_fwd(r1p, yB, nullptr, h1, nullptr, 0.f);          // c3 -> h1

  // ---------- Layer 2: h1 (16,16,128) -> code (16384,256) ----------
  auto l2_fwd = [&](const unsigned short* src, const unsigned short* Y, const unsigned short* Cp,
                    unsigned short* Cout, unsigned short* Yout, float cf){
    LA_nhwc al{src, 4,4,7};
    EpiM ep{}; ep.C=Cout; ep.Y=Y; ep.Cprev=Cp; ep.Yout=Yout; ep.coef=cf;
    dim3 g(2, 128, 1);
    if (Y) mgemm_k<LA_nhwc,EPI_UPDATE><<<g,512,0,stream>>>(al, wT2, 16384,256,2048, ep);
    else   mgemm_k<LA_nhwc,EPI_FIRST ><<<g,512,0,stream>>>(al, wT2, 16384,256,2048, ep);
  };
  auto l2_tconv = [&](const unsigned short* y){
    LA_yg al{y, 3,3,8, 0,0};
    EpiM ep{}; ep.C=rH; ep.img=h1; ep.lH=4; ep.lW=4; ep.lC=7;
    mgemm_k<LA_yg,EPI_RES_NHWC><<<dim3(1,128,4),512,0,stream>>>(al, wcls2, 16384,128,1024, ep);
  };
  l2_fwd(h1, nullptr, nullptr, cA, nullptr, 0.f);
  l2_tconv(cA);
  l2_fwd(rH, cA, cA, cB, yA, coef[2]);
  l2_tconv(yA);
  l2_fwd(rH, yA, cB, cA, yB, coef[3]);
  l2_tconv(yB);
  l2_fwd(rH, yB, nullptr, cB, nullptr, 0.f);           // pre-BN
  hipMemsetAsync(bnsum, 0, 2*256*sizeof(float), stream);
  bn_stats_k<<<256,256,0,stream>>>(cB, bnsum, 16384, 256);
  bn_apply_k<<<2048,256,0,stream>>>(cB, bnsum, g2, b2, h2, 16384, 256, 1.f/16384.f);

  // ---------- Layer 3: h2 (8,8,256) -> code (4096,512), split-K S=4 ----------
  auto l3_fwd = [&](const unsigned short* src, const unsigned short* Y, const unsigned short* Cp,
                    unsigned short* Cout, unsigned short* Yout, float cf){
    LA_nhwc al{src, 3,3,8};
    EpiM ep{}; ep.C=partL3; ep.S_MN=4096*512; ep.Kc=1024;
    mgemm_k<LA_nhwc,EPI_PARTIAL><<<dim3(4,32,4),512,0,stream>>>(al, wT3, 4096,512,4096, ep);
    splitk_shrink_k<<<1024,256,0,stream>>>(partL3, Y, Cout, Yout, Cp, cf, 4096*512, 4);
  };
  auto l3_tconv = [&](const unsigned short* y){
    LA_yg al{y, 2,2,9, 0,0};
    EpiM ep{}; ep.C=rH; ep.img=h2; ep.lH=3; ep.lW=3; ep.lC=8;
    mgemm_k<LA_yg,EPI_RES_NHWC><<<dim3(2,32,4),512,0,stream>>>(al, wcls3, 4096,256,2048, ep);
  };
  l3_fwd(h2, nullptr, nullptr, cA, nullptr, 0.f);
  l3_tconv(cA);
  l3_fwd(rH, cA, cA, cB, yA, coef[2]);
  l3_tconv(yA);
  l3_fwd(rH, yA, cB, cA, yB, coef[3]);
  l3_tconv(yB);
  l3_fwd(rH, yB, nullptr, cB, nullptr, 0.f);
  hipMemsetAsync(bnsum, 0, 2*512*sizeof(float), stream);
  bn_stats_k<<<256,256,0,stream>>>(cB, bnsum, 4096, 512);
  bn_apply_k<<<2048,256,0,stream>>>(cB, bnsum, g3, b3, h3, 4096, 512, 1.f/4096.f);

  // ---------- Layer 4: flat (256,8192) -> (256,256), split-K S=32 ----------
  auto l4_fwd = [&](const unsigned short* Asrc, const unsigned short* Y, const unsigned short* Cp,
                    unsigned short* Cout, unsigned short* Yout, float cf){
    LA_ident al{Asrc, 8192};
    EpiM ep{}; ep.C=partL4; ep.S_MN=65536; ep.Kc=256;
    mgemm_k<LA_ident,EPI_PARTIAL><<<dim3(2,2,32),512,0,stream>>>(al, wT4, 256,256,8192, ep);
    splitk_shrink_k<<<256,256,0,stream>>>(partL4, Y, Cout, Yout, Cp, cf, 65536, 32);
  };
  auto l4_tconv = [&](const unsigned short* y){
    LA_ident al{y, 256};
    EpiM ep{}; ep.C=rH; ep.img=h3;
    mgemm_k<LA_ident,EPI_RES_FLAT><<<dim3(64,2,1),512,0,stream>>>(al, wE4, 256,8192,256, ep);
  };
  l4_fwd(h3, nullptr, nullptr, cA, nullptr, 0.f);
  l4_tconv(cA);
  l4_fwd(rH, cA, cA, cB, yA, coef[2]);
  l4_tconv(yA);
  l4_fwd(rH, yA, cB, cA, yB, coef[3]);
  l4_tconv(yB);
  l4_fwd(rH, yB, nullptr, cB, nullptr, 0.f);           // c3

  norm_rows_k<<<256,256,0,stream>>>(cB, out);
}